// Round 8
// baseline (159.153 us; speedup 1.0000x reference)
//
#include <hip/hip_runtime.h>

// Causal flash attention, B=4 L=S=2048 H=8 E=D=64, fp32 in/out, bf16 MFMA.
// Round 15: round-14 tile engine, re-partitioned for time-balance. Round-14
// profile: Occ 13.6% (launch 8 waves/CU) -- the short paired block finishes
// early and the long block runs ALONE for ~30 tiles (1 wave/SIMD, all latency
// exposed). Fix: 2-wave blocks on strip pairs (2t,2t+1) (both need exactly
// tiles 0..t), grid 1024, LDS 32KB -> 5 blocks/CU all-resident, and the CU
// mapping t = idx<16 ? 31-idx : idx-16 gives every CU blocks of (32-c),
// (24-c), (c+1), (c+9) tiles = 66 total, staggered finishes, ~8-tile tail.
//  - K/V staged once per block into LDS via async global_load_lds from the
//    frag-major bf16 workspace (lane-linear = gload_lds dest constraint;
//    ds_read_b128 conflict-free). Double-buffered, counted vmcnt(8), raw
//    s_barrier (NOT __syncthreads), rule-#18 sched_barrier fences.
//  - Per-wave tile math round-9/14 verbatim (HW-verified): swapped QK^T,
//    in-lane softmax, pack2+permlane32_swap P-frags, defer-max THR=8,
//    mask trigger kt==ktend (dt==t for both waves of the pair).

typedef unsigned short u16;
typedef unsigned int   u32;
typedef short short8   __attribute__((ext_vector_type(8)));
typedef float floatx16 __attribute__((ext_vector_type(16)));
typedef u32 u32x4      __attribute__((ext_vector_type(4)));

#define B_ 4
#define L_ 2048
#define S_ 2048
#define H_ 8
#define E_ 64
#define D_ 64

// round-half-up fp32->bf16 pair, lo in low 16 bits
static __device__ __forceinline__ u32 pack2(float lo, float hi) {
    const u32 a = __float_as_uint(lo) + 0x8000u;
    const u32 b = __float_as_uint(hi) + 0x8000u;
    return __builtin_amdgcn_perm(b, a, 0x07060302u);
}
static __device__ __forceinline__ u16 bf16c(float x) {
    return (u16)((__float_as_uint(x) + 0x8000u) >> 16);
}
// v_permlane32_swap_b32: a.hi32lanes <-> b.lo32lanes
static __device__ __forceinline__ void pl32swap(u32& a, u32& b) {
    asm("v_permlane32_swap_b32 %0, %1" : "+v"(a), "+v"(b));
}
static __device__ __forceinline__ floatx16 zero16() {
    floatx16 z;
    #pragma unroll
    for (int i = 0; i < 16; i++) z[i] = 0.f;
    return z;
}
// async 16B-per-lane global -> LDS (dest = uniform base + lane*16)
static __device__ __forceinline__ void gload_lds16(u16* lds, const u16* g) {
    __builtin_amdgcn_global_load_lds((const __attribute__((address_space(1))) void*)g,
                                     (__attribute__((address_space(3))) void*)lds,
                                     16, 0, 0);
}

// ---------------- pre-pass: fp32 -> bf16, FRAG-MAJOR tiles ----------------
// Kc tile (per bh,kt; 4096 u16): [F=mt*4+ks][lane=hi*32+l31][j]
//   holds K[b][s=kt*64+mt*32+l31][h][e=ks*16+hi*8+j]
// Vt tile (per bh,kt; 4096 u16): [F=nt*4+ks][lane=hi*32+l31][j]
//   holds V[b][s=kt*64+ks*16+hi*8+j][h][d=nt*32+l31]
__global__ __launch_bounds__(256)
void cvt_kernel(const float* __restrict__ k, const float* __restrict__ v,
                u16* __restrict__ kc, u16* __restrict__ vt)
{
    __shared__ u16 Lt[64 * 72];
    const int bx = blockIdx.x, t = threadIdx.x;
    const int tile = bx & 1023;
    const int kt = tile & 31, h = (tile >> 5) & 7, b = tile >> 8;
    const int F  = t >> 5;
    const int hi = (t >> 4) & 1;
    const int l0 = (t & 15) * 2;

    if (bx < 1024) {
        const int mt = F >> 2, ks = F & 3;
        const int s  = kt * 64 + mt * 32 + l0;
        const int e  = ks * 16 + hi * 8;
        const float* p0 = k + (((size_t)(b * S_ + s)) * H_ + h) * E_ + e;
        const float4 a0 = ((const float4*)p0)[0], a1 = ((const float4*)p0)[1];
        const float* p1 = p0 + H_ * E_;
        const float4 b0 = ((const float4*)p1)[0], b1 = ((const float4*)p1)[1];
        u16* dst = kc + ((size_t)(b * 8 + h)) * 131072 + (size_t)kt * 4096 + t * 16;
        *(u32x4*)dst = (u32x4){pack2(a0.x, a0.y), pack2(a0.z, a0.w),
                               pack2(a1.x, a1.y), pack2(a1.z, a1.w)};
        *(u32x4*)(dst + 8) = (u32x4){pack2(b0.x, b0.y), pack2(b0.z, b0.w),
                                     pack2(b1.x, b1.y), pack2(b1.z, b1.w)};
    } else {
        {
            const int i  = t >> 2;
            const int d0 = (t & 3) * 16;
            const float* vp = v + (((size_t)(b * S_ + kt * 64 + i)) * H_ + h) * D_ + d0;
            const float4 a0 = ((const float4*)vp)[0], a1 = ((const float4*)vp)[1];
            const float4 a2 = ((const float4*)vp)[2], a3 = ((const float4*)vp)[3];
            const float va[16] = {a0.x,a0.y,a0.z,a0.w, a1.x,a1.y,a1.z,a1.w,
                                  a2.x,a2.y,a2.z,a2.w, a3.x,a3.y,a3.z,a3.w};
            #pragma unroll
            for (int jj = 0; jj < 16; jj++) Lt[(d0 + jj) * 72 + i] = bf16c(va[jj]);
        }
        __syncthreads();
        {
            const int nt = F >> 2, ks = F & 3;
            const int d1 = nt * 32 + l0;
            u16* dst = vt + ((size_t)(b * 8 + h)) * 131072 + (size_t)kt * 4096 + t * 16;
            *(u32x4*)dst       = *(const u32x4*)&Lt[(d1    ) * 72 + ks * 16 + hi * 8];
            *(u32x4*)(dst + 8) = *(const u32x4*)&Lt[(d1 + 1) * 72 + ks * 16 + hi * 8];
        }
    }
}

// ---------------- main kernel ----------------
// Grid 1024 x 128thr (2 waves). bx bits: [0:2]=h, [3:4]=b, [5:9]=idx.
// t = idx<16 ? 31-idx : idx-16  (per-CU tile sums constant = 66).
// Wave w -> strip 2t+w, rows q0 = 64t+32w .. +31; tiles kt = 0..t shared
// via LDS-staged K/V (both strips need exactly the same k-range).
template<int SRC>
__global__ __launch_bounds__(128, 2)
void fa_kernel(const float* __restrict__ q, const float* __restrict__ kk,
               const float* __restrict__ vv, const u16* __restrict__ kc,
               const u16* __restrict__ vt, float* __restrict__ out)
{
    __shared__ __align__(16) u16 KV[2][8192];   // [buf][K 8 frags | V 8 frags]

    const int tid  = threadIdx.x;
    const int w    = tid >> 6;
    const int lane = tid & 63;
    const int l31  = lane & 31;
    const int hi   = lane >> 5;

    const int bx   = blockIdx.x;
    const int h    = bx & 7;
    const int b    = (bx >> 3) & 3;
    const int idx  = bx >> 5;                    // 0..31
    const int t    = (idx < 16) ? (31 - idx) : (idx - 16);
    const int q0   = 64 * t + 32 * w;
    const int ktend = t;                         // tiles 0..t; diag == last

    const float kscale = 0.18033688011112042f; // (1/sqrt(64)) * log2(e)

    // ---- Q frags (B-operand of S^T = K*Q^T), kscale folded ----
    const float* qptr = q + (((size_t)b * L_ + q0 + l31) * H_ + h) * E_ + hi * 8;
    short8 qf[4];
    #pragma unroll
    for (int ks = 0; ks < 4; ks++) {
        const float4 a0 = *(const float4*)(qptr + ks * 16);
        const float4 a1 = *(const float4*)(qptr + ks * 16 + 4);
        const u32x4 u = {pack2(a0.x * kscale, a0.y * kscale), pack2(a0.z * kscale, a0.w * kscale),
                         pack2(a1.x * kscale, a1.y * kscale), pack2(a1.z * kscale, a1.w * kscale)};
        qf[ks] = __builtin_bit_cast(short8, u);
    }

    const size_t bh = (size_t)(b * 8 + h);
    const u16* kcb = kc + bh * 131072;
    const u16* vtb = vt + bh * 131072;

    // async stage: wave w moves K frags {4w..4w+3} and V frags {4w..4w+3}
    auto stage = [&](int kt, int bufi) {
        #pragma unroll
        for (int ff = 0; ff < 4; ff++) {
            const int f = w * 4 + ff;
            gload_lds16(&KV[bufi][f * 512],        kcb + (size_t)kt * 4096 + f * 512 + lane * 8);
            gload_lds16(&KV[bufi][4096 + f * 512], vtb + (size_t)kt * 4096 + f * 512 + lane * 8);
        }
    };
    // sync fallback stage (no workspace): fp32 loads + pack + ds_write
    auto stage_sync = [&](int kt) {
        #pragma unroll
        for (int ff = 0; ff < 4; ff++) {
            const int f = w * 4 + ff;
            const int mt = f >> 2, ks = f & 3;
            const float* p = kk + (((size_t)b * S_ + kt * 64 + mt * 32 + l31) * H_ + h) * E_ + ks * 16 + hi * 8;
            const float4 a0 = *(const float4*)p;
            const float4 a1 = *(const float4*)(p + 4);
            *(u32x4*)&KV[0][f * 512 + lane * 8] =
                (u32x4){pack2(a0.x, a0.y), pack2(a0.z, a0.w), pack2(a1.x, a1.y), pack2(a1.z, a1.w)};
            float fv[8];
            #pragma unroll
            for (int jj = 0; jj < 8; jj++)
                fv[jj] = vv[(((size_t)b * S_ + kt * 64 + ks * 16 + hi * 8 + jj) * H_ + h) * D_ + mt * 32 + l31];
            *(u32x4*)&KV[0][4096 + f * 512 + lane * 8] =
                (u32x4){pack2(fv[0], fv[1]), pack2(fv[2], fv[3]), pack2(fv[4], fv[5]), pack2(fv[6], fv[7])};
        }
    };

    floatx16 occ[2] = {zero16(), zero16()};  // O^T: col = q = l31
    float m_run = -1e30f, l_run = 0.f;

    // ---- prologue ----
    if constexpr (SRC == 0) {
        stage(0, 0);
        asm volatile("s_waitcnt vmcnt(0)" ::: "memory");
        __builtin_amdgcn_s_barrier();
        __builtin_amdgcn_sched_barrier(0);   // first-tile reads stay below
    }

    for (int kt = 0; kt <= ktend; kt++) {
        int cur;
        if constexpr (SRC == 0) {
            cur = kt & 1;
            if (kt < ktend) {
                stage(kt + 1, cur ^ 1);                            // async, in flight
                asm volatile("s_waitcnt vmcnt(8)" ::: "memory");   // tile kt's 8 done
            } else {
                asm volatile("s_waitcnt vmcnt(0)" ::: "memory");
            }
            __builtin_amdgcn_s_barrier();                          // tile kt in LDS
            __builtin_amdgcn_sched_barrier(0);                     // no hoist above sync
        } else {
            cur = 0;
            stage_sync(kt);
            __syncthreads();
        }

        // ---- load 16 frags from LDS (lane-linear ds_read_b128) ----
        short8 kfr[2][4], vfr[2][4];
        #pragma unroll
        for (int mt = 0; mt < 2; mt++)
            #pragma unroll
            for (int ks = 0; ks < 4; ks++) {
                kfr[mt][ks] = *(const short8*)&KV[cur][(mt * 4 + ks) * 512 + lane * 8];
                vfr[mt][ks] = *(const short8*)&KV[cur][4096 + (mt * 4 + ks) * 512 + lane * 8];
            }

        // ---- S^T = K*Q^T ----
        floatx16 sac[2];
        __builtin_amdgcn_s_setprio(1);
        #pragma unroll
        for (int mt = 0; mt < 2; mt++) {
            floatx16 c = zero16();
            #pragma unroll
            for (int ks = 0; ks < 4; ks++)
                c = __builtin_amdgcn_mfma_f32_32x32x16_bf16(kfr[mt][ks], qf[ks], c, 0, 0, 0);
            sac[mt] = c;
        }
        __builtin_amdgcn_s_setprio(0);

        // ---- causal mask (diagonal == last tile for both waves) ----
        if (kt == ktend) {
            const int qg = q0 + l31;
            #pragma unroll
            for (int mt = 0; mt < 2; mt++)
                #pragma unroll
                for (int r = 0; r < 16; r++) {
                    const int keyg = kt * 64 + mt * 32 + (r & 3) + (r >> 2) * 8 + hi * 4;
                    if (keyg > qg) sac[mt][r] = -1e30f;
                }
        }

        // ---- online softmax, in-lane + 1 shfl; defer-max (THR=8) ----
        float red[16];
        #pragma unroll
        for (int r = 0; r < 16; r++) red[r] = fmaxf(sac[0][r], sac[1][r]);
        #pragma unroll
        for (int stp = 8; stp > 0; stp >>= 1)
            #pragma unroll
            for (int r = 0; r < stp; r++) red[r] = fmaxf(red[r], red[r + stp]);
        const float mx = fmaxf(red[0], __shfl_xor(red[0], 32));

        const bool defer = __all(mx - m_run <= 8.0f) != 0;
        if (!defer) {
            const float mnew  = fmaxf(m_run, mx);
            const float alpha = exp2f(m_run - mnew);
            m_run = mnew;
            l_run *= alpha;
            #pragma unroll
            for (int r = 0; r < 16; r++) { occ[0][r] *= alpha; occ[1][r] *= alpha; }
        }

        float sum[16];
        #pragma unroll
        for (int r = 0; r < 16; r++) {
            sac[0][r] = exp2f(sac[0][r] - m_run);
            sac[1][r] = exp2f(sac[1][r] - m_run);
            sum[r] = sac[0][r] + sac[1][r];
        }
        #pragma unroll
        for (int stp = 8; stp > 0; stp >>= 1)
            #pragma unroll
            for (int r = 0; r < stp; r++) sum[r] += sum[r + stp];
        l_run += sum[0] + __shfl_xor(sum[0], 32);

        // ---- P -> bf16 pairs ----
        u32 pk0[8], pk1[8];
        #pragma unroll
        for (int r2 = 0; r2 < 4; r2++) {
            pk0[2 * r2 + 0] = pack2(sac[0][4 * r2 + 0], sac[0][4 * r2 + 1]);
            pk0[2 * r2 + 1] = pack2(sac[0][4 * r2 + 2], sac[0][4 * r2 + 3]);
            pk1[2 * r2 + 0] = pack2(sac[1][4 * r2 + 0], sac[1][4 * r2 + 1]);
            pk1[2 * r2 + 1] = pack2(sac[1][4 * r2 + 2], sac[1][4 * r2 + 3]);
        }

        // ---- O^T += V^T * P (permlane32_swap builds B-frags) ----
        __builtin_amdgcn_s_setprio(1);
        #pragma unroll
        for (int ks = 0; ks < 4; ks++) {
            const int u = (ks & 1) * 4;
            u32 w0, w1, w2, w3;
            if (ks < 2) { w0 = pk0[u]; w1 = pk0[u + 1]; w2 = pk0[u + 2]; w3 = pk0[u + 3]; }
            else        { w0 = pk1[u]; w1 = pk1[u + 1]; w2 = pk1[u + 2]; w3 = pk1[u + 3]; }
            pl32swap(w0, w2);
            pl32swap(w1, w3);
            const u32x4 pw = {w0, w1, w2, w3};
            const short8 pf = __builtin_bit_cast(short8, pw);
            occ[0] = __builtin_amdgcn_mfma_f32_32x32x16_bf16(vfr[0][ks], pf, occ[0], 0, 0, 0);
            occ[1] = __builtin_amdgcn_mfma_f32_32x32x16_bf16(vfr[1][ks], pf, occ[1], 0, 0, 0);
        }
        __builtin_amdgcn_s_setprio(0);

        // ---- end-of-tile barrier: both waves done reading KV[cur] ----
        if constexpr (SRC == 0) {
            __builtin_amdgcn_sched_barrier(0);   // no sink below into next tile
            __builtin_amdgcn_s_barrier();
        } else {
            __syncthreads();
        }
    }

    // ---- epilogue: O = O^T / l ----
    const float inv = 1.0f / l_run;
    float* op = out + (((size_t)b * L_ + q0 + l31) * H_ + h) * D_;
    #pragma unroll
    for (int nt = 0; nt < 2; nt++)
        #pragma unroll
        for (int r2 = 0; r2 < 4; r2++) {
            const float4 o = {occ[nt][4 * r2 + 0] * inv, occ[nt][4 * r2 + 1] * inv,
                              occ[nt][4 * r2 + 2] * inv, occ[nt][4 * r2 + 3] * inv};
            *(float4*)(op + nt * 32 + r2 * 8 + hi * 4) = o;
        }
}

extern "C" void kernel_launch(void* const* d_in, const int* in_sizes, int n_in,
                              void* d_out, int out_size, void* d_ws, size_t ws_size,
                              hipStream_t stream) {
    const float* q = (const float*)d_in[0];
    const float* k = (const float*)d_in[1];
    const float* v = (const float*)d_in[2];
    // d_in[3] = attn_mask: fixed causal triu -> handled analytically in-kernel.
    float* out = (float*)d_out;

    const size_t elems = (size_t)B_ * H_ * S_ * E_;   // per tensor (u16 count)
    const size_t need  = elems * 2 * 2;               // Kc + Vt, bf16
    if (d_ws != nullptr && ws_size >= need) {
        u16* kc = (u16*)d_ws;
        u16* vt = kc + elems;
        cvt_kernel<<<dim3(2048), dim3(256), 0, stream>>>(k, v, kc, vt);
        fa_kernel<0><<<dim3(1024), dim3(128), 0, stream>>>(q, k, v, kc, vt, out);
    } else {
        fa_kernel<1><<<dim3(1024), dim3(128), 0, stream>>>(q, k, v, nullptr, nullptr, out);
    }
}

// Round 9
// 156.880 us; speedup vs baseline: 1.0145x; 1.0145x over previous
//
#include <hip/hip_runtime.h>

// Causal flash attention, B=4 L=S=2048 H=8 E=D=64, fp32 in/out, bf16 MFMA.
// Round 16: in-block SPLIT-K for wave supply. R9/R14/R15 all pinned at
// Occ ~13%: only ~2048 waves exist (1 per 32 q-rows) -> ~1 wave/SIMD by
// mid-kernel, every latency exposed (65us vs the ~23us VALU-issue floor
// measured from VALUBusy). Fix: block = 4 waves on ONE 32-row strip with the
// k-range split 4 ways (chains <= 8 tiles, was 33); partial (m,l,O) merged
// via an exact LDS tree at block end. 8192 waves total, 4/SIMD resident
// (VGPR<=128 via LB(256,4)), 2048 blocks with big-T first for backfill.
//  - NO K/V LDS staging (waves read different tiles): direct frag-major
//    loads from the bf16 workspace (R9-verified, coalesced 1KB bursts).
//    NO main-loop barriers at all; 4 __syncthreads only in the merge.
//  - Per-wave tile math round-9/14 verbatim (HW-verified): swapped QK^T,
//    in-lane softmax, pack2+permlane32_swap P-frags, defer-max THR=8,
//    mask only on kt == T-1 (diag tile of a 32-row strip).
//  - Merge: m=max, a=exp2(m_i-m), l=sum a*l_i, O=sum a*O_i -- exact.

typedef unsigned short u16;
typedef unsigned int   u32;
typedef short short8   __attribute__((ext_vector_type(8)));
typedef float floatx16 __attribute__((ext_vector_type(16)));
typedef u32 u32x4      __attribute__((ext_vector_type(4)));

#define B_ 4
#define L_ 2048
#define S_ 2048
#define H_ 8
#define E_ 64
#define D_ 64

// round-half-up fp32->bf16 pair, lo in low 16 bits
static __device__ __forceinline__ u32 pack2(float lo, float hi) {
    const u32 a = __float_as_uint(lo) + 0x8000u;
    const u32 b = __float_as_uint(hi) + 0x8000u;
    return __builtin_amdgcn_perm(b, a, 0x07060302u);
}
static __device__ __forceinline__ u16 bf16c(float x) {
    return (u16)((__float_as_uint(x) + 0x8000u) >> 16);
}
// v_permlane32_swap_b32: a.hi32lanes <-> b.lo32lanes
static __device__ __forceinline__ void pl32swap(u32& a, u32& b) {
    asm("v_permlane32_swap_b32 %0, %1" : "+v"(a), "+v"(b));
}
static __device__ __forceinline__ floatx16 zero16() {
    floatx16 z;
    #pragma unroll
    for (int i = 0; i < 16; i++) z[i] = 0.f;
    return z;
}

// ---------------- pre-pass: fp32 -> bf16, FRAG-MAJOR tiles ----------------
// Kc tile (per bh,kt; 4096 u16): [F=mt*4+ks][lane=hi*32+l31][j]
//   holds K[b][s=kt*64+mt*32+l31][h][e=ks*16+hi*8+j]
// Vt tile (per bh,kt; 4096 u16): [F=nt*4+ks][lane=hi*32+l31][j]
//   holds V[b][s=kt*64+ks*16+hi*8+j][h][d=nt*32+l31]
__global__ __launch_bounds__(256)
void cvt_kernel(const float* __restrict__ k, const float* __restrict__ v,
                u16* __restrict__ kc, u16* __restrict__ vt)
{
    __shared__ u16 Lt[64 * 72];
    const int bx = blockIdx.x, t = threadIdx.x;
    const int tile = bx & 1023;
    const int kt = tile & 31, h = (tile >> 5) & 7, b = tile >> 8;
    const int F  = t >> 5;
    const int hi = (t >> 4) & 1;
    const int l0 = (t & 15) * 2;

    if (bx < 1024) {
        const int mt = F >> 2, ks = F & 3;
        const int s  = kt * 64 + mt * 32 + l0;
        const int e  = ks * 16 + hi * 8;
        const float* p0 = k + (((size_t)(b * S_ + s)) * H_ + h) * E_ + e;
        const float4 a0 = ((const float4*)p0)[0], a1 = ((const float4*)p0)[1];
        const float* p1 = p0 + H_ * E_;
        const float4 b0 = ((const float4*)p1)[0], b1 = ((const float4*)p1)[1];
        u16* dst = kc + ((size_t)(b * 8 + h)) * 131072 + (size_t)kt * 4096 + t * 16;
        *(u32x4*)dst = (u32x4){pack2(a0.x, a0.y), pack2(a0.z, a0.w),
                               pack2(a1.x, a1.y), pack2(a1.z, a1.w)};
        *(u32x4*)(dst + 8) = (u32x4){pack2(b0.x, b0.y), pack2(b0.z, b0.w),
                                     pack2(b1.x, b1.y), pack2(b1.z, b1.w)};
    } else {
        {
            const int i  = t >> 2;
            const int d0 = (t & 3) * 16;
            const float* vp = v + (((size_t)(b * S_ + kt * 64 + i)) * H_ + h) * D_ + d0;
            const float4 a0 = ((const float4*)vp)[0], a1 = ((const float4*)vp)[1];
            const float4 a2 = ((const float4*)vp)[2], a3 = ((const float4*)vp)[3];
            const float va[16] = {a0.x,a0.y,a0.z,a0.w, a1.x,a1.y,a1.z,a1.w,
                                  a2.x,a2.y,a2.z,a2.w, a3.x,a3.y,a3.z,a3.w};
            #pragma unroll
            for (int jj = 0; jj < 16; jj++) Lt[(d0 + jj) * 72 + i] = bf16c(va[jj]);
        }
        __syncthreads();
        {
            const int nt = F >> 2, ks = F & 3;
            const int d1 = nt * 32 + l0;
            u16* dst = vt + ((size_t)(b * 8 + h)) * 131072 + (size_t)kt * 4096 + t * 16;
            *(u32x4*)dst       = *(const u32x4*)&Lt[(d1    ) * 72 + ks * 16 + hi * 8];
            *(u32x4*)(dst + 8) = *(const u32x4*)&Lt[(d1 + 1) * 72 + ks * 16 + hi * 8];
        }
    }
}

// ---------------- main kernel ----------------
// Grid 2048 x 256thr (4 waves). bx bits: [0:2]=h, [3:4]=b, [5:10]=ss.
// s = 63-ss (big strips dispatched first). Block covers strip rows
// q0=32s..32s+31; T = s/2+1 k-tiles split 4 ways: wave w gets
// [w*C, min((w+1)C, T)), C = ceil(T/4) <= 8. LDS merge tree at end.
template<int SRC>
__global__ __launch_bounds__(256, 4)
void fa_kernel(const float* __restrict__ q, const float* __restrict__ kk,
               const float* __restrict__ vv, const u16* __restrict__ kc,
               const u16* __restrict__ vt, float* __restrict__ out)
{
    __shared__ float Ms[2][2176];   // [slot][(nt*16+r)*64+lane | 2048+m | 2112+l]

    const int tid  = threadIdx.x;
    const int w    = tid >> 6;
    const int lane = tid & 63;
    const int l31  = lane & 31;
    const int hi   = lane >> 5;

    const int bx   = blockIdx.x;
    const int h    = bx & 7;
    const int b    = (bx >> 3) & 3;
    const int ss   = bx >> 5;                 // 0..63
    const int s    = 63 - ss;                 // strip; big first
    const int T    = (s >> 1) + 1;            // k-tiles for this strip
    const int Tm1  = T - 1;
    const int q0   = 32 * s;
    const int C    = (T + 3) >> 2;
    const int kt0  = w * C;
    const int kt1  = min(kt0 + C, T);

    const float kscale = 0.18033688011112042f; // (1/sqrt(64)) * log2(e)

    // ---- Q frags (B-operand of S^T = K*Q^T), kscale folded ----
    const float* qptr = q + (((size_t)b * L_ + q0 + l31) * H_ + h) * E_ + hi * 8;
    short8 qf[4];
    #pragma unroll
    for (int ks = 0; ks < 4; ks++) {
        const float4 a0 = *(const float4*)(qptr + ks * 16);
        const float4 a1 = *(const float4*)(qptr + ks * 16 + 4);
        const u32x4 u = {pack2(a0.x * kscale, a0.y * kscale), pack2(a0.z * kscale, a0.w * kscale),
                         pack2(a1.x * kscale, a1.y * kscale), pack2(a1.z * kscale, a1.w * kscale)};
        qf[ks] = __builtin_bit_cast(short8, u);
    }

    const size_t bh = (size_t)(b * 8 + h);
    const u16* kcb = kc + bh * 131072;
    const u16* vtb = vt + bh * 131072;

    auto loadK = [&](int kt, int mt, int ks) -> short8 {
        if constexpr (SRC == 0) {
            const u32x4 u = *(const u32x4*)&kcb[(size_t)kt * 4096 + (mt * 4 + ks) * 512 + lane * 8];
            return __builtin_bit_cast(short8, u);
        } else {
            const float* p = kk + (((size_t)b * S_ + kt * 64 + mt * 32 + l31) * H_ + h) * E_ + ks * 16 + hi * 8;
            const float4 a0 = *(const float4*)p;
            const float4 a1 = *(const float4*)(p + 4);
            const u32x4 u = {pack2(a0.x, a0.y), pack2(a0.z, a0.w), pack2(a1.x, a1.y), pack2(a1.z, a1.w)};
            return __builtin_bit_cast(short8, u);
        }
    };
    auto loadV = [&](int kt, int nt, int ks) -> short8 {
        if constexpr (SRC == 0) {
            const u32x4 u = *(const u32x4*)&vtb[(size_t)kt * 4096 + (nt * 4 + ks) * 512 + lane * 8];
            return __builtin_bit_cast(short8, u);
        } else {
            float f[8];
            #pragma unroll
            for (int jj = 0; jj < 8; jj++)
                f[jj] = vv[(((size_t)b * S_ + kt * 64 + ks * 16 + hi * 8 + jj) * H_ + h) * D_ + nt * 32 + l31];
            const u32x4 u = {pack2(f[0], f[1]), pack2(f[2], f[3]), pack2(f[4], f[5]), pack2(f[6], f[7])};
            return __builtin_bit_cast(short8, u);
        }
    };

    floatx16 occ[2] = {zero16(), zero16()};  // O^T: col = q = l31
    float m_run = -1e30f, l_run = 0.f;

    for (int kt = kt0; kt < kt1; kt++) {
        // ---- K frags + S^T = K*Q^T ----
        short8 kfr[2][4];
        #pragma unroll
        for (int mt = 0; mt < 2; mt++)
            #pragma unroll
            for (int ks = 0; ks < 4; ks++) kfr[mt][ks] = loadK(kt, mt, ks);

        floatx16 sac[2];
        __builtin_amdgcn_s_setprio(1);
        #pragma unroll
        for (int mt = 0; mt < 2; mt++) {
            floatx16 c = zero16();
            #pragma unroll
            for (int ks = 0; ks < 4; ks++)
                c = __builtin_amdgcn_mfma_f32_32x32x16_bf16(kfr[mt][ks], qf[ks], c, 0, 0, 0);
            sac[mt] = c;
        }
        __builtin_amdgcn_s_setprio(0);

        // ---- V frags issued now; latency hides under softmax ----
        short8 vfr[2][4];
        #pragma unroll
        for (int nt = 0; nt < 2; nt++)
            #pragma unroll
            for (int ks = 0; ks < 4; ks++) vfr[nt][ks] = loadV(kt, nt, ks);

        // ---- causal mask (diagonal tile only) ----
        if (kt == Tm1) {
            const int qg = q0 + l31;
            #pragma unroll
            for (int mt = 0; mt < 2; mt++)
                #pragma unroll
                for (int r = 0; r < 16; r++) {
                    const int keyg = kt * 64 + mt * 32 + (r & 3) + (r >> 2) * 8 + hi * 4;
                    if (keyg > qg) sac[mt][r] = -1e30f;
                }
        }

        // ---- online softmax, in-lane + 1 shfl; defer-max (THR=8) ----
        float red[16];
        #pragma unroll
        for (int r = 0; r < 16; r++) red[r] = fmaxf(sac[0][r], sac[1][r]);
        #pragma unroll
        for (int stp = 8; stp > 0; stp >>= 1)
            #pragma unroll
            for (int r = 0; r < stp; r++) red[r] = fmaxf(red[r], red[r + stp]);
        const float mx = fmaxf(red[0], __shfl_xor(red[0], 32));

        const bool defer = __all(mx - m_run <= 8.0f) != 0;
        if (!defer) {
            const float mnew  = fmaxf(m_run, mx);
            const float alpha = exp2f(m_run - mnew);
            m_run = mnew;
            l_run *= alpha;
            #pragma unroll
            for (int r = 0; r < 16; r++) { occ[0][r] *= alpha; occ[1][r] *= alpha; }
        }

        float sum[16];
        #pragma unroll
        for (int r = 0; r < 16; r++) {
            sac[0][r] = exp2f(sac[0][r] - m_run);
            sac[1][r] = exp2f(sac[1][r] - m_run);
            sum[r] = sac[0][r] + sac[1][r];
        }
        #pragma unroll
        for (int stp = 8; stp > 0; stp >>= 1)
            #pragma unroll
            for (int r = 0; r < stp; r++) sum[r] += sum[r + stp];
        l_run += sum[0] + __shfl_xor(sum[0], 32);

        // ---- P -> bf16 pairs ----
        u32 pk0[8], pk1[8];
        #pragma unroll
        for (int r2 = 0; r2 < 4; r2++) {
            pk0[2 * r2 + 0] = pack2(sac[0][4 * r2 + 0], sac[0][4 * r2 + 1]);
            pk0[2 * r2 + 1] = pack2(sac[0][4 * r2 + 2], sac[0][4 * r2 + 3]);
            pk1[2 * r2 + 0] = pack2(sac[1][4 * r2 + 0], sac[1][4 * r2 + 1]);
            pk1[2 * r2 + 1] = pack2(sac[1][4 * r2 + 2], sac[1][4 * r2 + 3]);
        }

        // ---- O^T += V^T * P (permlane32_swap builds B-frags) ----
        __builtin_amdgcn_s_setprio(1);
        #pragma unroll
        for (int ks = 0; ks < 4; ks++) {
            const int u = (ks & 1) * 4;
            u32 w0, w1, w2, w3;
            if (ks < 2) { w0 = pk0[u]; w1 = pk0[u + 1]; w2 = pk0[u + 2]; w3 = pk0[u + 3]; }
            else        { w0 = pk1[u]; w1 = pk1[u + 1]; w2 = pk1[u + 2]; w3 = pk1[u + 3]; }
            pl32swap(w0, w2);
            pl32swap(w1, w3);
            const u32x4 pw = {w0, w1, w2, w3};
            const short8 pf = __builtin_bit_cast(short8, pw);
            occ[0] = __builtin_amdgcn_mfma_f32_32x32x16_bf16(vfr[0][ks], pf, occ[0], 0, 0, 0);
            occ[1] = __builtin_amdgcn_mfma_f32_32x32x16_bf16(vfr[1][ks], pf, occ[1], 0, 0, 0);
        }
        __builtin_amdgcn_s_setprio(0);
    }

    // ---- merge tree: (w1->w0), (w3->w2), then (w2->w0); exact math ----
    auto dump = [&](int slot) {
        #pragma unroll
        for (int nt = 0; nt < 2; nt++)
            #pragma unroll
            for (int r = 0; r < 16; r++) Ms[slot][(nt * 16 + r) * 64 + lane] = occ[nt][r];
        Ms[slot][2048 + lane] = m_run;
        Ms[slot][2112 + lane] = l_run;
    };
    auto mergeIn = [&](int slot) {
        const float mB = Ms[slot][2048 + lane], lB = Ms[slot][2112 + lane];
        const float m  = fmaxf(m_run, mB);
        const float aA = exp2f(m_run - m), aB = exp2f(mB - m);
        m_run = m;
        l_run = l_run * aA + lB * aB;
        #pragma unroll
        for (int nt = 0; nt < 2; nt++)
            #pragma unroll
            for (int r = 0; r < 16; r++)
                occ[nt][r] = occ[nt][r] * aA + Ms[slot][(nt * 16 + r) * 64 + lane] * aB;
    };

    __syncthreads();
    if (w == 1 || w == 3) dump(w >> 1);
    __syncthreads();
    if (w == 0 || w == 2) mergeIn(w >> 1);
    __syncthreads();
    if (w == 2) dump(1);
    __syncthreads();
    if (w == 0) {
        mergeIn(1);
        const float inv = 1.0f / l_run;
        float* op = out + (((size_t)b * L_ + q0 + l31) * H_ + h) * D_;
        #pragma unroll
        for (int nt = 0; nt < 2; nt++)
            #pragma unroll
            for (int r2 = 0; r2 < 4; r2++) {
                const float4 o = {occ[nt][4 * r2 + 0] * inv, occ[nt][4 * r2 + 1] * inv,
                                  occ[nt][4 * r2 + 2] * inv, occ[nt][4 * r2 + 3] * inv};
                *(float4*)(op + nt * 32 + r2 * 8 + hi * 4) = o;
            }
    }
}

extern "C" void kernel_launch(void* const* d_in, const int* in_sizes, int n_in,
                              void* d_out, int out_size, void* d_ws, size_t ws_size,
                              hipStream_t stream) {
    const float* q = (const float*)d_in[0];
    const float* k = (const float*)d_in[1];
    const float* v = (const float*)d_in[2];
    // d_in[3] = attn_mask: fixed causal triu -> handled analytically in-kernel.
    float* out = (float*)d_out;

    const size_t elems = (size_t)B_ * H_ * S_ * E_;   // per tensor (u16 count)
    const size_t need  = elems * 2 * 2;               // Kc + Vt, bf16
    if (d_ws != nullptr && ws_size >= need) {
        u16* kc = (u16*)d_ws;
        u16* vt = kc + elems;
        cvt_kernel<<<dim3(2048), dim3(256), 0, stream>>>(k, v, kc, vt);
        fa_kernel<0><<<dim3(2048), dim3(256), 0, stream>>>(q, k, v, kc, vt, out);
    } else {
        fa_kernel<1><<<dim3(2048), dim3(256), 0, stream>>>(q, k, v, nullptr, nullptr, out);
    }
}

// Round 10
// 141.067 us; speedup vs baseline: 1.1282x; 1.1121x over previous
//
#include <hip/hip_runtime.h>

// Causal flash attention, B=4 L=S=2048 H=8 E=D=64, fp32 in/out, bf16 MFMA.
// Round 17 = round 16 with the REGISTER BUDGET fixed. R16 post-mortem: the
// split-K structure delivered its occupancy (13->35%) but WRITE_SIZE went
// 16.4 -> 50.8 MB and FETCH doubled = scratch SPILLS in the inner loop.
// LB(256,4) capped the unified reg file at 512/4 = 128 (reported 64 VGPR +
// 64 acc = exactly the cap) while the live set (sac+pk+kfr+vfr+qf) needs
// ~150. Fix: LB(256,3) -> cap ~170, live set fits, 3 blocks/CU = 12 waves
// resident (same ~35% occupancy we measured, now without scratch traffic).
//  - Block = 4 waves on ONE 32-row strip, k-range split 4 ways (chains <= 8
//    tiles); exact (m,l,O) LDS merge tree at block end. 8192 waves total.
//  - NO K/V LDS staging (waves read different tiles): direct frag-major
//    loads from the bf16 workspace (coalesced 1KB bursts, L2-resident).
//    NO main-loop barriers; 4 __syncthreads only in the merge.
//  - Per-wave tile math round-9/14 verbatim (HW-verified): swapped QK^T,
//    in-lane softmax, pack2+permlane32_swap P-frags, defer-max THR=8,
//    mask only on kt == T-1.

typedef unsigned short u16;
typedef unsigned int   u32;
typedef short short8   __attribute__((ext_vector_type(8)));
typedef float floatx16 __attribute__((ext_vector_type(16)));
typedef u32 u32x4      __attribute__((ext_vector_type(4)));

#define B_ 4
#define L_ 2048
#define S_ 2048
#define H_ 8
#define E_ 64
#define D_ 64

// round-half-up fp32->bf16 pair, lo in low 16 bits
static __device__ __forceinline__ u32 pack2(float lo, float hi) {
    const u32 a = __float_as_uint(lo) + 0x8000u;
    const u32 b = __float_as_uint(hi) + 0x8000u;
    return __builtin_amdgcn_perm(b, a, 0x07060302u);
}
static __device__ __forceinline__ u16 bf16c(float x) {
    return (u16)((__float_as_uint(x) + 0x8000u) >> 16);
}
// v_permlane32_swap_b32: a.hi32lanes <-> b.lo32lanes
static __device__ __forceinline__ void pl32swap(u32& a, u32& b) {
    asm("v_permlane32_swap_b32 %0, %1" : "+v"(a), "+v"(b));
}
static __device__ __forceinline__ floatx16 zero16() {
    floatx16 z;
    #pragma unroll
    for (int i = 0; i < 16; i++) z[i] = 0.f;
    return z;
}

// ---------------- pre-pass: fp32 -> bf16, FRAG-MAJOR tiles ----------------
// Kc tile (per bh,kt; 4096 u16): [F=mt*4+ks][lane=hi*32+l31][j]
//   holds K[b][s=kt*64+mt*32+l31][h][e=ks*16+hi*8+j]
// Vt tile (per bh,kt; 4096 u16): [F=nt*4+ks][lane=hi*32+l31][j]
//   holds V[b][s=kt*64+ks*16+hi*8+j][h][d=nt*32+l31]
__global__ __launch_bounds__(256)
void cvt_kernel(const float* __restrict__ k, const float* __restrict__ v,
                u16* __restrict__ kc, u16* __restrict__ vt)
{
    __shared__ u16 Lt[64 * 72];
    const int bx = blockIdx.x, t = threadIdx.x;
    const int tile = bx & 1023;
    const int kt = tile & 31, h = (tile >> 5) & 7, b = tile >> 8;
    const int F  = t >> 5;
    const int hi = (t >> 4) & 1;
    const int l0 = (t & 15) * 2;

    if (bx < 1024) {
        const int mt = F >> 2, ks = F & 3;
        const int s  = kt * 64 + mt * 32 + l0;
        const int e  = ks * 16 + hi * 8;
        const float* p0 = k + (((size_t)(b * S_ + s)) * H_ + h) * E_ + e;
        const float4 a0 = ((const float4*)p0)[0], a1 = ((const float4*)p0)[1];
        const float* p1 = p0 + H_ * E_;
        const float4 b0 = ((const float4*)p1)[0], b1 = ((const float4*)p1)[1];
        u16* dst = kc + ((size_t)(b * 8 + h)) * 131072 + (size_t)kt * 4096 + t * 16;
        *(u32x4*)dst = (u32x4){pack2(a0.x, a0.y), pack2(a0.z, a0.w),
                               pack2(a1.x, a1.y), pack2(a1.z, a1.w)};
        *(u32x4*)(dst + 8) = (u32x4){pack2(b0.x, b0.y), pack2(b0.z, b0.w),
                                     pack2(b1.x, b1.y), pack2(b1.z, b1.w)};
    } else {
        {
            const int i  = t >> 2;
            const int d0 = (t & 3) * 16;
            const float* vp = v + (((size_t)(b * S_ + kt * 64 + i)) * H_ + h) * D_ + d0;
            const float4 a0 = ((const float4*)vp)[0], a1 = ((const float4*)vp)[1];
            const float4 a2 = ((const float4*)vp)[2], a3 = ((const float4*)vp)[3];
            const float va[16] = {a0.x,a0.y,a0.z,a0.w, a1.x,a1.y,a1.z,a1.w,
                                  a2.x,a2.y,a2.z,a2.w, a3.x,a3.y,a3.z,a3.w};
            #pragma unroll
            for (int jj = 0; jj < 16; jj++) Lt[(d0 + jj) * 72 + i] = bf16c(va[jj]);
        }
        __syncthreads();
        {
            const int nt = F >> 2, ks = F & 3;
            const int d1 = nt * 32 + l0;
            u16* dst = vt + ((size_t)(b * 8 + h)) * 131072 + (size_t)kt * 4096 + t * 16;
            *(u32x4*)dst       = *(const u32x4*)&Lt[(d1    ) * 72 + ks * 16 + hi * 8];
            *(u32x4*)(dst + 8) = *(const u32x4*)&Lt[(d1 + 1) * 72 + ks * 16 + hi * 8];
        }
    }
}

// ---------------- main kernel ----------------
// Grid 2048 x 256thr (4 waves). bx bits: [0:2]=h, [3:4]=b, [5:10]=ss.
// s = 63-ss (big strips dispatched first). Block covers strip rows
// q0=32s..32s+31; T = s/2+1 k-tiles split 4 ways: wave w gets
// [w*C, min((w+1)C, T)), C = ceil(T/4) <= 8. LDS merge tree at end.
template<int SRC>
__global__ __launch_bounds__(256, 3)
void fa_kernel(const float* __restrict__ q, const float* __restrict__ kk,
               const float* __restrict__ vv, const u16* __restrict__ kc,
               const u16* __restrict__ vt, float* __restrict__ out)
{
    __shared__ float Ms[2][2176];   // [slot][(nt*16+r)*64+lane | 2048+m | 2112+l]

    const int tid  = threadIdx.x;
    const int w    = tid >> 6;
    const int lane = tid & 63;
    const int l31  = lane & 31;
    const int hi   = lane >> 5;

    const int bx   = blockIdx.x;
    const int h    = bx & 7;
    const int b    = (bx >> 3) & 3;
    const int ss   = bx >> 5;                 // 0..63
    const int s    = 63 - ss;                 // strip; big first
    const int T    = (s >> 1) + 1;            // k-tiles for this strip
    const int Tm1  = T - 1;
    const int q0   = 32 * s;
    const int C    = (T + 3) >> 2;
    const int kt0  = w * C;
    const int kt1  = min(kt0 + C, T);

    const float kscale = 0.18033688011112042f; // (1/sqrt(64)) * log2(e)

    // ---- Q frags (B-operand of S^T = K*Q^T), kscale folded ----
    const float* qptr = q + (((size_t)b * L_ + q0 + l31) * H_ + h) * E_ + hi * 8;
    short8 qf[4];
    #pragma unroll
    for (int ks = 0; ks < 4; ks++) {
        const float4 a0 = *(const float4*)(qptr + ks * 16);
        const float4 a1 = *(const float4*)(qptr + ks * 16 + 4);
        const u32x4 u = {pack2(a0.x * kscale, a0.y * kscale), pack2(a0.z * kscale, a0.w * kscale),
                         pack2(a1.x * kscale, a1.y * kscale), pack2(a1.z * kscale, a1.w * kscale)};
        qf[ks] = __builtin_bit_cast(short8, u);
    }

    const size_t bh = (size_t)(b * 8 + h);
    const u16* kcb = kc + bh * 131072;
    const u16* vtb = vt + bh * 131072;

    auto loadK = [&](int kt, int mt, int ks) -> short8 {
        if constexpr (SRC == 0) {
            const u32x4 u = *(const u32x4*)&kcb[(size_t)kt * 4096 + (mt * 4 + ks) * 512 + lane * 8];
            return __builtin_bit_cast(short8, u);
        } else {
            const float* p = kk + (((size_t)b * S_ + kt * 64 + mt * 32 + l31) * H_ + h) * E_ + ks * 16 + hi * 8;
            const float4 a0 = *(const float4*)p;
            const float4 a1 = *(const float4*)(p + 4);
            const u32x4 u = {pack2(a0.x, a0.y), pack2(a0.z, a0.w), pack2(a1.x, a1.y), pack2(a1.z, a1.w)};
            return __builtin_bit_cast(short8, u);
        }
    };
    auto loadV = [&](int kt, int nt, int ks) -> short8 {
        if constexpr (SRC == 0) {
            const u32x4 u = *(const u32x4*)&vtb[(size_t)kt * 4096 + (nt * 4 + ks) * 512 + lane * 8];
            return __builtin_bit_cast(short8, u);
        } else {
            float f[8];
            #pragma unroll
            for (int jj = 0; jj < 8; jj++)
                f[jj] = vv[(((size_t)b * S_ + kt * 64 + ks * 16 + hi * 8 + jj) * H_ + h) * D_ + nt * 32 + l31];
            const u32x4 u = {pack2(f[0], f[1]), pack2(f[2], f[3]), pack2(f[4], f[5]), pack2(f[6], f[7])};
            return __builtin_bit_cast(short8, u);
        }
    };

    floatx16 occ[2] = {zero16(), zero16()};  // O^T: col = q = l31
    float m_run = -1e30f, l_run = 0.f;

    for (int kt = kt0; kt < kt1; kt++) {
        // ---- K frags + S^T = K*Q^T ----
        short8 kfr[2][4];
        #pragma unroll
        for (int mt = 0; mt < 2; mt++)
            #pragma unroll
            for (int ks = 0; ks < 4; ks++) kfr[mt][ks] = loadK(kt, mt, ks);

        floatx16 sac[2];
        __builtin_amdgcn_s_setprio(1);
        #pragma unroll
        for (int mt = 0; mt < 2; mt++) {
            floatx16 c = zero16();
            #pragma unroll
            for (int ks = 0; ks < 4; ks++)
                c = __builtin_amdgcn_mfma_f32_32x32x16_bf16(kfr[mt][ks], qf[ks], c, 0, 0, 0);
            sac[mt] = c;
        }
        __builtin_amdgcn_s_setprio(0);

        // ---- V frags issued now; latency hides under softmax ----
        short8 vfr[2][4];
        #pragma unroll
        for (int nt = 0; nt < 2; nt++)
            #pragma unroll
            for (int ks = 0; ks < 4; ks++) vfr[nt][ks] = loadV(kt, nt, ks);

        // ---- causal mask (diagonal tile only) ----
        if (kt == Tm1) {
            const int qg = q0 + l31;
            #pragma unroll
            for (int mt = 0; mt < 2; mt++)
                #pragma unroll
                for (int r = 0; r < 16; r++) {
                    const int keyg = kt * 64 + mt * 32 + (r & 3) + (r >> 2) * 8 + hi * 4;
                    if (keyg > qg) sac[mt][r] = -1e30f;
                }
        }

        // ---- online softmax, in-lane + 1 shfl; defer-max (THR=8) ----
        float red[16];
        #pragma unroll
        for (int r = 0; r < 16; r++) red[r] = fmaxf(sac[0][r], sac[1][r]);
        #pragma unroll
        for (int stp = 8; stp > 0; stp >>= 1)
            #pragma unroll
            for (int r = 0; r < stp; r++) red[r] = fmaxf(red[r], red[r + stp]);
        const float mx = fmaxf(red[0], __shfl_xor(red[0], 32));

        const bool defer = __all(mx - m_run <= 8.0f) != 0;
        if (!defer) {
            const float mnew  = fmaxf(m_run, mx);
            const float alpha = exp2f(m_run - mnew);
            m_run = mnew;
            l_run *= alpha;
            #pragma unroll
            for (int r = 0; r < 16; r++) { occ[0][r] *= alpha; occ[1][r] *= alpha; }
        }

        float sum[16];
        #pragma unroll
        for (int r = 0; r < 16; r++) {
            sac[0][r] = exp2f(sac[0][r] - m_run);
            sac[1][r] = exp2f(sac[1][r] - m_run);
            sum[r] = sac[0][r] + sac[1][r];
        }
        #pragma unroll
        for (int stp = 8; stp > 0; stp >>= 1)
            #pragma unroll
            for (int r = 0; r < stp; r++) sum[r] += sum[r + stp];
        l_run += sum[0] + __shfl_xor(sum[0], 32);

        // ---- P -> bf16 pairs ----
        u32 pk0[8], pk1[8];
        #pragma unroll
        for (int r2 = 0; r2 < 4; r2++) {
            pk0[2 * r2 + 0] = pack2(sac[0][4 * r2 + 0], sac[0][4 * r2 + 1]);
            pk0[2 * r2 + 1] = pack2(sac[0][4 * r2 + 2], sac[0][4 * r2 + 3]);
            pk1[2 * r2 + 0] = pack2(sac[1][4 * r2 + 0], sac[1][4 * r2 + 1]);
            pk1[2 * r2 + 1] = pack2(sac[1][4 * r2 + 2], sac[1][4 * r2 + 3]);
        }

        // ---- O^T += V^T * P (permlane32_swap builds B-frags) ----
        __builtin_amdgcn_s_setprio(1);
        #pragma unroll
        for (int ks = 0; ks < 4; ks++) {
            const int u = (ks & 1) * 4;
            u32 w0, w1, w2, w3;
            if (ks < 2) { w0 = pk0[u]; w1 = pk0[u + 1]; w2 = pk0[u + 2]; w3 = pk0[u + 3]; }
            else        { w0 = pk1[u]; w1 = pk1[u + 1]; w2 = pk1[u + 2]; w3 = pk1[u + 3]; }
            pl32swap(w0, w2);
            pl32swap(w1, w3);
            const u32x4 pw = {w0, w1, w2, w3};
            const short8 pf = __builtin_bit_cast(short8, pw);
            occ[0] = __builtin_amdgcn_mfma_f32_32x32x16_bf16(vfr[0][ks], pf, occ[0], 0, 0, 0);
            occ[1] = __builtin_amdgcn_mfma_f32_32x32x16_bf16(vfr[1][ks], pf, occ[1], 0, 0, 0);
        }
        __builtin_amdgcn_s_setprio(0);
    }

    // ---- merge tree: (w1->w0), (w3->w2), then (w2->w0); exact math ----
    auto dump = [&](int slot) {
        #pragma unroll
        for (int nt = 0; nt < 2; nt++)
            #pragma unroll
            for (int r = 0; r < 16; r++) Ms[slot][(nt * 16 + r) * 64 + lane] = occ[nt][r];
        Ms[slot][2048 + lane] = m_run;
        Ms[slot][2112 + lane] = l_run;
    };
    auto mergeIn = [&](int slot) {
        const float mB = Ms[slot][2048 + lane], lB = Ms[slot][2112 + lane];
        const float m  = fmaxf(m_run, mB);
        const float aA = exp2f(m_run - m), aB = exp2f(mB - m);
        m_run = m;
        l_run = l_run * aA + lB * aB;
        #pragma unroll
        for (int nt = 0; nt < 2; nt++)
            #pragma unroll
            for (int r = 0; r < 16; r++)
                occ[nt][r] = occ[nt][r] * aA + Ms[slot][(nt * 16 + r) * 64 + lane] * aB;
    };

    __syncthreads();
    if (w == 1 || w == 3) dump(w >> 1);
    __syncthreads();
    if (w == 0 || w == 2) mergeIn(w >> 1);
    __syncthreads();
    if (w == 2) dump(1);
    __syncthreads();
    if (w == 0) {
        mergeIn(1);
        const float inv = 1.0f / l_run;
        float* op = out + (((size_t)b * L_ + q0 + l31) * H_ + h) * D_;
        #pragma unroll
        for (int nt = 0; nt < 2; nt++)
            #pragma unroll
            for (int r2 = 0; r2 < 4; r2++) {
                const float4 o = {occ[nt][4 * r2 + 0] * inv, occ[nt][4 * r2 + 1] * inv,
                                  occ[nt][4 * r2 + 2] * inv, occ[nt][4 * r2 + 3] * inv};
                *(float4*)(op + nt * 32 + r2 * 8 + hi * 4) = o;
            }
    }
}

extern "C" void kernel_launch(void* const* d_in, const int* in_sizes, int n_in,
                              void* d_out, int out_size, void* d_ws, size_t ws_size,
                              hipStream_t stream) {
    const float* q = (const float*)d_in[0];
    const float* k = (const float*)d_in[1];
    const float* v = (const float*)d_in[2];
    // d_in[3] = attn_mask: fixed causal triu -> handled analytically in-kernel.
    float* out = (float*)d_out;

    const size_t elems = (size_t)B_ * H_ * S_ * E_;   // per tensor (u16 count)
    const size_t need  = elems * 2 * 2;               // Kc + Vt, bf16
    if (d_ws != nullptr && ws_size >= need) {
        u16* kc = (u16*)d_ws;
        u16* vt = kc + elems;
        cvt_kernel<<<dim3(2048), dim3(256), 0, stream>>>(k, v, kc, vt);
        fa_kernel<0><<<dim3(2048), dim3(256), 0, stream>>>(q, k, v, kc, vt, out);
    } else {
        fa_kernel<1><<<dim3(2048), dim3(256), 0, stream>>>(q, k, v, nullptr, nullptr, out);
    }
}